// Round 8
// baseline (1076.690 us; speedup 1.0000x reference)
//
#include <hip/hip_runtime.h>
#include <hip/hip_cooperative_groups.h>
#include <math.h>

namespace cg = cooperative_groups;

#define SLOT 128      // fixed CSR slot capacity per node (max in-degree Poisson(33) << 128)

__device__ __forceinline__ float leaky02(float x){ return x > 0.f ? x : 0.2f * x; }
__device__ __forceinline__ float eluf(float x){ return x > 0.f ? x : expm1f(x); }

struct Params {
  const float* x; const int* srcv; const int* dstv; const int* batch;
  const float* W1; const float* a_src1; const float* a_dst1; const float* b1;
  const float* W2; const float* a_src2; const float* a_dst2; const float* b2;
  const float* Wc1; const float* bc1; const float* Wc2; const float* bc2;
  float* outp;
  float* h1; float* act1; float* h2;
  float* as1; float* ad1; float* as2; float* ad2;
  int* cursor; int* colv; float* pooled;
  int N, E, G;
};

// ---- GAT aggregation phase (wave-private slots, barrier-free, slot-CSR) ------------
template<int CTOT, int H, bool POOL>
__device__ void aggr_phase(const Params& p, const float* __restrict__ feat,
                           const float* __restrict__ as_, const float* __restrict__ ad_,
                           const float* __restrict__ bias, float* __restrict__ out,
                           int bid, int nbk, int t, int* s_off, float* s_p)
{
  constexpr int L = CTOT / 4, NPW = 64 / L, NPB = 4 * NPW, CH = CTOT / H, CHUNK = L;
  constexpr int OSTR = CHUNK + 1, PSTR = CHUNK * H + 1;
  const int wave = t >> 6, lane = t & 63;
  const int grp = lane / L, li = lane % L;
  const int slot = wave * NPW + grp;
  const int hc = (4 * li) / CH;
  int*   so = s_off + slot * OSTR;
  float* sp = s_p + slot * PSTR;
  const int n = p.N;
  const int ngroups = (n + NPB - 1) / NPB;

  for (int gi = bid; gi < ngroups; gi += nbk) {
    const int node = gi * NPB + slot;
    if (node < n) {
      const int beg = node * SLOT;
      const int deg = min(p.cursor[node], SLOT);

      float adv[H], eself[H];
      #pragma unroll
      for (int h = 0; h < H; ++h) adv[h] = ad_[node * H + h];
      #pragma unroll
      for (int h = 0; h < H; ++h) eself[h] = leaky02(as_[node * H + h] + adv[h]);
      float es = 0.f;
      #pragma unroll
      for (int h = 0; h < H; ++h) if (h == hc) es = eself[h];
      const float psf = expf(es);

      const float4 fs = *(const float4*)(feat + (size_t)node * CTOT + 4 * li);
      double a64[4];
      a64[0] = (double)psf * (double)fs.x;
      a64[1] = (double)psf * (double)fs.y;
      a64[2] = (double)psf * (double)fs.z;
      a64[3] = (double)psf * (double)fs.w;
      double den = (double)psf;

      for (int base = 0; base < deg; base += CHUNK) {
        const int cnt = min(CHUNK, deg - base);
        if (li < cnt) {
          int s = p.colv[beg + base + li];
          so[li] = s * CTOT;
          if constexpr (H == 4) {
            float4 q = ((const float4*)as_)[s];
            sp[li * 4 + 0] = expf(leaky02(q.x + adv[0]));
            sp[li * 4 + 1] = expf(leaky02(q.y + adv[1]));
            sp[li * 4 + 2] = expf(leaky02(q.z + adv[2]));
            sp[li * 4 + 3] = expf(leaky02(q.w + adv[3]));
          } else {
            sp[li] = expf(leaky02(as_[s] + adv[0]));
          }
        }
        __builtin_amdgcn_wave_barrier();
        float a0 = 0.f, a1 = 0.f, a2 = 0.f, a3 = 0.f, df = 0.f;
        #pragma unroll 4
        for (int j = 0; j < cnt; ++j) {
          int off = so[j];
          float pv = (H == 4) ? sp[j * 4 + hc] : sp[j];
          const float4 f = *(const float4*)(feat + off + 4 * li);
          a0 += pv * f.x; a1 += pv * f.y; a2 += pv * f.z; a3 += pv * f.w;
          df += pv;
        }
        __builtin_amdgcn_wave_barrier();
        a64[0] += a0; a64[1] += a1; a64[2] += a2; a64[3] += a3;
        den += df;
      }

      const float4 bv = *(const float4*)(bias + 4 * li);
      float4 o;
      o.x = eluf((float)(a64[0] / den) + bv.x);
      o.y = eluf((float)(a64[1] / den) + bv.y);
      o.z = eluf((float)(a64[2] / den) + bv.z);
      o.w = eluf((float)(a64[3] / den) + bv.w);
      if (POOL) {
        int g = p.batch[node];
        float* pp = p.pooled + (size_t)g * 32 + 4 * li;
        atomicAdd(pp + 0, o.x);
        atomicAdd(pp + 1, o.y);
        atomicAdd(pp + 2, o.z);
        atomicAdd(pp + 3, o.w);
      } else {
        *(float4*)(out + (size_t)node * CTOT + 4 * li) = o;
      }
    }
  }
}

// ------------------------------- mega kernel ----------------------------------------
__global__ __launch_bounds__(256, 4) void mega_kernel(Params p)
{
  cg::grid_group grid = cg::this_grid();
  const int t   = threadIdx.x;
  const int bid = blockIdx.x;
  const int nbk = gridDim.x;
  const int gtid = bid * 256 + t;
  const int gsz  = nbk * 256;

  __shared__ int   s_offF[320];    // max(8*33, 32*9)
  __shared__ float s_pF[1056];     // max(8*129, 32*9)

  // ---- Phase A: zero cursor + pooled ----
  for (int i = gtid; i < p.N; i += gsz) p.cursor[i] = 0;
  for (int i = gtid; i < p.G * 32; i += gsz) p.pooled[i] = 0.f;
  grid.sync();

  // ---- Phase B: CSR fill (atomic/memory-bound) then gemm1 (VALU-bound), no barrier
  for (int e = gtid; e < p.E; e += gsz) {
    int d = p.dstv[e];
    int pos = atomicAdd(&p.cursor[d], 1);
    if (pos < SLOT) p.colv[(size_t)d * SLOT + pos] = p.srcv[e];
  }
  {
    const int ntiles = (p.N + 15) / 16;
    const int col  = t & 127;
    const int rblk = __builtin_amdgcn_readfirstlane(t >> 7);  // force wave-uniform
    const int lane = t & 63;
    const float asv = p.a_src1[col], adv = p.a_dst1[col];
    for (int tile = bid; tile < ntiles; tile += nbk) {
      const int row0 = tile * 16 + rblk * 8;
      const float* xr[8];
      #pragma unroll
      for (int r = 0; r < 8; ++r) {
        int rr = row0 + r; if (rr >= p.N) rr = p.N - 1;
        xr[r] = p.x + (size_t)rr * 128;
      }
      float acc[8] = {0,0,0,0,0,0,0,0};
      #pragma unroll 4
      for (int k = 0; k < 128; ++k) {
        float w = p.W1[k * 128 + col];
        #pragma unroll
        for (int r = 0; r < 8; ++r) acc[r] += xr[r][k] * w;   // xr uniform -> s_load
      }
      float ps[8], pd[8];
      #pragma unroll
      for (int r = 0; r < 8; ++r) {
        if (row0 + r < p.N) p.h1[(size_t)(row0 + r) * 128 + col] = acc[r];
        ps[r] = acc[r] * asv;
        pd[r] = acc[r] * adv;
      }
      #pragma unroll
      for (int off = 16; off >= 1; off >>= 1) {
        #pragma unroll
        for (int r = 0; r < 8; ++r) {
          ps[r] += __shfl_xor(ps[r], off);
          pd[r] += __shfl_xor(pd[r], off);
        }
      }
      if ((lane & 31) == 0) {
        const int head = col >> 5;
        #pragma unroll
        for (int r = 0; r < 8; ++r) {
          if (row0 + r < p.N) {
            p.as1[(row0 + r) * 4 + head] = ps[r];
            p.ad1[(row0 + r) * 4 + head] = pd[r];
          }
        }
      }
    }
  }
  grid.sync();

  // ---- Phase C: layer-1 aggregation ----
  aggr_phase<128, 4, false>(p, p.h1, p.as1, p.ad1, p.b1, p.act1, bid, nbk, t, s_offF, s_pF);
  grid.sync();

  // ---- Phase D: gemm2 (wave-per-row) ----
  {
    const int wave = __builtin_amdgcn_readfirstlane(t >> 6);
    const int lane = t & 63, col = lane & 31, kh = lane >> 5;
    const int ngr = (p.N + 3) / 4;
    for (int gb = bid; gb < ngr; gb += nbk) {
      const int row = gb * 4 + wave;
      if (row < p.N) {
        const float* xrp = p.act1 + (size_t)row * 128 + kh * 64;
        const float* Wp  = p.W2 + (kh * 64) * 32 + col;
        float acc = 0.f;
        #pragma unroll 8
        for (int k = 0; k < 64; ++k) acc += xrp[k] * Wp[k * 32];
        acc += __shfl_xor(acc, 32);
        if (kh == 0) p.h2[(size_t)row * 32 + col] = acc;
        float s = acc * p.a_src2[col];
        float d = acc * p.a_dst2[col];
        #pragma unroll
        for (int off = 16; off >= 1; off >>= 1) {
          s += __shfl_xor(s, off);
          d += __shfl_xor(d, off);
        }
        if (lane == 0) { p.as2[row] = s; p.ad2[row] = d; }
      }
    }
  }
  grid.sync();

  // ---- Phase E: layer-2 aggregation fused with mean-pool atomics ----
  aggr_phase<32, 1, true>(p, p.h2, p.as2, p.ad2, p.b2, nullptr, bid, nbk, t, s_offF, s_pF);
  grid.sync();

  // ---- Phase F: per-graph count (binary search on sorted batch) + classifier ----
  for (int g = gtid; g < p.G; g += gsz) {
    int lo = 0, hi = p.N;
    while (lo < hi) { int m = (lo + hi) >> 1; if (p.batch[m] <  g) lo = m + 1; else hi = m; }
    int lo2 = lo, hi2 = p.N;
    while (lo2 < hi2) { int m = (lo2 + hi2) >> 1; if (p.batch[m] < g + 1) lo2 = m + 1; else hi2 = m; }
    const int cntg = hi2 - lo;
    const float inv = cntg > 0 ? 1.0f / (float)cntg : 0.f;
    float pm[32];
    for (int c = 0; c < 32; ++c) pm[c] = p.pooled[(size_t)g * 32 + c] * inv;
    double o = (double)p.bc2[0];
    for (int j = 0; j < 16; ++j) {
      double z = (double)p.bc1[j];
      for (int c = 0; c < 32; ++c) z += (double)pm[c] * (double)p.Wc1[c * 16 + j];
      float zr = (float)z;
      zr = zr > 0.f ? zr : 0.f;
      o += (double)zr * (double)p.Wc2[j];
    }
    p.outp[g] = (float)o;
  }
}

// ===================== fallback multi-kernel pipeline (R6, known-good) ==============
__global__ __launch_bounds__(128) void gemm1_kernel(
    const float* __restrict__ x, const float* __restrict__ W,
    const float* __restrict__ a_src, const float* __restrict__ a_dst,
    float* __restrict__ h, float* __restrict__ as_, float* __restrict__ ad_, int n)
{
  const int t = threadIdx.x;
  const int row0 = blockIdx.x * 8;
  __shared__ float sS[8][128];
  __shared__ float sD[8][128];
  const float* xr[8];
  #pragma unroll
  for (int r = 0; r < 8; ++r) {
    int rr = row0 + r; if (rr >= n) rr = n - 1;
    xr[r] = x + (size_t)rr * 128;
  }
  float acc[8] = {0,0,0,0,0,0,0,0};
  #pragma unroll 4
  for (int k = 0; k < 128; ++k) {
    float w = W[k * 128 + t];
    #pragma unroll
    for (int r = 0; r < 8; ++r) acc[r] += xr[r][k] * w;
  }
  float asv = a_src[t], adv = a_dst[t];
  #pragma unroll
  for (int r = 0; r < 8; ++r) {
    float hv = acc[r];
    if (row0 + r < n) h[(size_t)(row0 + r) * 128 + t] = hv;
    sS[r][t] = hv * asv;
    sD[r][t] = hv * adv;
  }
  __syncthreads();
  if (t < 64) {
    int r = t >> 3, head = t & 3, which = (t >> 2) & 1;
    if (row0 + r < n) {
      const float (*buf)[128] = which ? sD : sS;
      double s = 0;
      for (int cc = 0; cc < 32; ++cc) s += (double)buf[r][head * 32 + cc];
      float* dstp = which ? ad_ : as_;
      dstp[(row0 + r) * 4 + head] = (float)s;
    }
  }
}

__global__ __launch_bounds__(256) void gemm2_kernel(
    const float* __restrict__ x, const float* __restrict__ W,
    const float* __restrict__ a_src, const float* __restrict__ a_dst,
    float* __restrict__ h, float* __restrict__ as_, float* __restrict__ ad_, int n)
{
  const int t = threadIdx.x;
  const int wave = t >> 6, lane = t & 63;
  const int col = lane & 31, kh = lane >> 5;
  const int row = blockIdx.x * 4 + wave;
  if (row >= n) return;
  const float* xrp = x + (size_t)row * 128 + kh * 64;
  const float* Wp  = W + (kh * 64) * 32 + col;
  float acc = 0.f;
  #pragma unroll 8
  for (int k = 0; k < 64; ++k) acc += xrp[k] * Wp[k * 32];
  acc += __shfl_xor(acc, 32);
  if (kh == 0) h[(size_t)row * 32 + col] = acc;
  float s = acc * a_src[col];
  float d = acc * a_dst[col];
  #pragma unroll
  for (int off = 16; off >= 1; off >>= 1) {
    s += __shfl_xor(s, off);
    d += __shfl_xor(d, off);
  }
  if (lane == 0) { as_[row] = s; ad_[row] = d; }
}

__global__ void fill_direct_kernel(const int* __restrict__ src, const int* __restrict__ dst,
    int* __restrict__ cursor, int* __restrict__ col, int E)
{
  int e = blockIdx.x * blockDim.x + threadIdx.x;
  if (e < E) {
    int d = dst[e];
    int pos = atomicAdd(&cursor[d], 1);
    if (pos < SLOT) col[(size_t)d * SLOT + pos] = src[e];
  }
}

template<int CTOT, int H>
__global__ __launch_bounds__(256) void gat_aggr3_kernel(
    const float* __restrict__ feat, const float* __restrict__ as_,
    const float* __restrict__ ad_, const int* __restrict__ cursor,
    const int* __restrict__ col, const float* __restrict__ bias,
    float* __restrict__ out, int n)
{
  constexpr int L = CTOT / 4, NPW = 64 / L, NPB = 4 * NPW, CH = CTOT / H, CHUNK = L;
  const int t = threadIdx.x;
  const int wave = t >> 6, lane = t & 63;
  const int grp = lane / L, li = lane % L;
  const int slot = wave * NPW + grp;
  const int node = blockIdx.x * NPB + slot;
  const int hc = (4 * li) / CH;
  __shared__ int   s_off[NPB][CHUNK + 1];
  __shared__ float s_p[NPB][CHUNK * H + 1];
  if (node >= n) return;
  const int beg = node * SLOT;
  const int deg = min(cursor[node], SLOT);
  float adv[H], eself[H];
  #pragma unroll
  for (int h = 0; h < H; ++h) adv[h] = ad_[node * H + h];
  #pragma unroll
  for (int h = 0; h < H; ++h) eself[h] = leaky02(as_[node * H + h] + adv[h]);
  float es = 0.f;
  #pragma unroll
  for (int h = 0; h < H; ++h) if (h == hc) es = eself[h];
  const float ps = expf(es);
  const float4 fself = *(const float4*)(feat + (size_t)node * CTOT + 4 * li);
  double acc64[4];
  acc64[0] = (double)ps * (double)fself.x;
  acc64[1] = (double)ps * (double)fself.y;
  acc64[2] = (double)ps * (double)fself.z;
  acc64[3] = (double)ps * (double)fself.w;
  double den64 = (double)ps;
  for (int base = 0; base < deg; base += CHUNK) {
    const int cnt = min(CHUNK, deg - base);
    if (li < cnt) {
      int s = col[beg + base + li];
      s_off[slot][li] = s * CTOT;
      if constexpr (H == 4) {
        float4 q = ((const float4*)as_)[s];
        s_p[slot][li * 4 + 0] = expf(leaky02(q.x + adv[0]));
        s_p[slot][li * 4 + 1] = expf(leaky02(q.y + adv[1]));
        s_p[slot][li * 4 + 2] = expf(leaky02(q.z + adv[2]));
        s_p[slot][li * 4 + 3] = expf(leaky02(q.w + adv[3]));
      } else {
        s_p[slot][li] = expf(leaky02(as_[s] + adv[0]));
      }
    }
    __builtin_amdgcn_wave_barrier();
    float a0 = 0.f, a1 = 0.f, a2 = 0.f, a3 = 0.f, df = 0.f;
    #pragma unroll 4
    for (int j = 0; j < cnt; ++j) {
      int off = s_off[slot][j];
      float pv = (H == 4) ? s_p[slot][j * 4 + hc] : s_p[slot][j];
      const float4 f = *(const float4*)(feat + off + 4 * li);
      a0 += pv * f.x; a1 += pv * f.y; a2 += pv * f.z; a3 += pv * f.w;
      df += pv;
    }
    __builtin_amdgcn_wave_barrier();
    acc64[0] += a0; acc64[1] += a1; acc64[2] += a2; acc64[3] += a3;
    den64 += df;
  }
  const float4 bv = *(const float4*)(bias + 4 * li);
  float4 o;
  o.x = eluf((float)(acc64[0] / den64) + bv.x);
  o.y = eluf((float)(acc64[1] / den64) + bv.y);
  o.z = eluf((float)(acc64[2] / den64) + bv.z);
  o.w = eluf((float)(acc64[3] / den64) + bv.w);
  *(float4*)(out + (size_t)node * CTOT + 4 * li) = o;
}

__global__ __launch_bounds__(256) void pool_kernel(const float* __restrict__ act2,
    const int* __restrict__ batch, float* __restrict__ pooled,
    float* __restrict__ cnt, int n)
{
  int t = threadIdx.x;
  int c = t & 31, r = t >> 5;
  int n0 = blockIdx.x * 64 + r * 8;
  float run = 0.f; int gcur = -1; int len = 0;
  for (int i = 0; i < 8; ++i) {
    int nd = n0 + i;
    if (nd >= n) break;
    int gb = batch[nd];
    if (gb != gcur) {
      if (gcur >= 0) {
        atomicAdd(&pooled[gcur * 32 + c], run);
        if (c == 0) atomicAdd(&cnt[gcur], (float)len);
      }
      gcur = gb; run = 0.f; len = 0;
    }
    run += act2[(size_t)nd * 32 + c];
    len++;
  }
  if (gcur >= 0) {
    atomicAdd(&pooled[gcur * 32 + c], run);
    if (c == 0) atomicAdd(&cnt[gcur], (float)len);
  }
}

__global__ void classifier_kernel(const float* __restrict__ pooled, const float* __restrict__ cnt,
    const float* __restrict__ Wc1, const float* __restrict__ bc1,
    const float* __restrict__ Wc2, const float* __restrict__ bc2,
    float* __restrict__ outp, int g_total)
{
  int g = blockIdx.x * blockDim.x + threadIdx.x;
  if (g < g_total) {
    float inv = 1.0f / cnt[g];
    float pm[32];
    for (int c = 0; c < 32; ++c) pm[c] = pooled[g * 32 + c] * inv;
    double o = (double)bc2[0];
    for (int j = 0; j < 16; ++j) {
      double z = (double)bc1[j];
      for (int c = 0; c < 32; ++c) z += (double)pm[c] * (double)Wc1[c * 16 + j];
      float zr = (float)z;
      zr = zr > 0.f ? zr : 0.f;
      o += (double)zr * (double)Wc2[j];
    }
    outp[g] = (float)o;
  }
}

// ---------------- launch ------------------------------------------------------------
extern "C" void kernel_launch(void* const* d_in, const int* in_sizes, int n_in,
                              void* d_out, int out_size, void* d_ws, size_t ws_size,
                              hipStream_t stream)
{
  Params prm;
  prm.x      = (const float*)d_in[0];
  const int* ei = (const int*)d_in[1];
  prm.batch  = (const int*)d_in[3];
  prm.W1     = (const float*)d_in[4];
  prm.a_src1 = (const float*)d_in[5];
  prm.a_dst1 = (const float*)d_in[6];
  prm.b1     = (const float*)d_in[7];
  prm.W2     = (const float*)d_in[8];
  prm.a_src2 = (const float*)d_in[9];
  prm.a_dst2 = (const float*)d_in[10];
  prm.b2     = (const float*)d_in[11];
  prm.Wc1    = (const float*)d_in[12];
  prm.bc1    = (const float*)d_in[13];
  prm.Wc2    = (const float*)d_in[14];
  prm.bc2    = (const float*)d_in[15];
  prm.outp   = (float*)d_out;

  prm.N = in_sizes[0] / 128;
  prm.E = in_sizes[1] / 2;
  prm.G = out_size;
  prm.srcv = ei;
  prm.dstv = ei + prm.E;

  char* ws = (char*)d_ws;
  size_t off = 0;
  auto alloc = [&](size_t bytes) -> void* {
    void* ptr = ws + off;
    off += (bytes + 255) & ~(size_t)255;
    return ptr;
  };
  // zero region (contiguous; zeroed by mega phase A or by memset in fallback)
  char* zbase = (char*)alloc(0);
  prm.cursor = (int*)alloc((size_t)prm.N * 4);
  prm.pooled = (float*)alloc((size_t)prm.G * 32 * 4);
  float* cntG = (float*)alloc((size_t)prm.G * 4);
  size_t zbytes = (size_t)((char*)alloc(0) - zbase);
  // rest
  prm.h1     = (float*)alloc((size_t)prm.N * 128 * 4);
  prm.act1   = (float*)alloc((size_t)prm.N * 128 * 4);
  prm.h2     = (float*)alloc((size_t)prm.N * 32 * 4);
  float* act2 = (float*)alloc((size_t)prm.N * 32 * 4);
  prm.as1    = (float*)alloc((size_t)prm.N * 4 * 4);
  prm.ad1    = (float*)alloc((size_t)prm.N * 4 * 4);
  prm.as2    = (float*)alloc((size_t)prm.N * 4);
  prm.ad2    = (float*)alloc((size_t)prm.N * 4);
  prm.colv   = (int*)alloc((size_t)prm.N * SLOT * 4);

  // ---- size the cooperative grid from the runtime (capture-safe host queries) ----
  int maxPerCU = 0;
  hipError_t oe = hipOccupancyMaxActiveBlocksPerMultiprocessor(
      &maxPerCU, (const void*)mega_kernel, 256, 0);
  int nCU = 0;
  int dev = 0;
  hipGetDevice(&dev);
  hipDeviceGetAttribute(&nCU, hipDeviceAttributeMultiprocessorCount, dev);
  if (nCU <= 0) nCU = 256;

  hipError_t le = hipErrorUnknown;
  if (oe == hipSuccess && maxPerCU >= 1) {
    long grid = (long)maxPerCU * nCU;
    if (grid > 4096) grid = 4096;
    void* kargs[] = { (void*)&prm };
    le = hipLaunchCooperativeKernel((const void*)mega_kernel, dim3((int)grid), dim3(256),
                                    kargs, 0, stream);
  }

  if (le != hipSuccess) {
    // -------- fallback: known-good multi-kernel pipeline --------
    hipMemsetAsync(zbase, 0, zbytes, stream);
    fill_direct_kernel<<<(prm.E + 255) / 256, 256, 0, stream>>>(
        prm.srcv, prm.dstv, prm.cursor, prm.colv, prm.E);
    gemm1_kernel<<<(prm.N + 7) / 8, 128, 0, stream>>>(
        prm.x, prm.W1, prm.a_src1, prm.a_dst1, prm.h1, prm.as1, prm.ad1, prm.N);
    gat_aggr3_kernel<128, 4><<<(prm.N + 7) / 8, 256, 0, stream>>>(
        prm.h1, prm.as1, prm.ad1, prm.cursor, prm.colv, prm.b1, prm.act1, prm.N);
    gemm2_kernel<<<(prm.N + 3) / 4, 256, 0, stream>>>(
        prm.act1, prm.W2, prm.a_src2, prm.a_dst2, prm.h2, prm.as2, prm.ad2, prm.N);
    gat_aggr3_kernel<32, 1><<<(prm.N + 31) / 32, 256, 0, stream>>>(
        prm.h2, prm.as2, prm.ad2, prm.cursor, prm.colv, prm.b2, act2, prm.N);
    pool_kernel<<<(prm.N + 63) / 64, 256, 0, stream>>>(act2, prm.batch, prm.pooled, cntG, prm.N);
    classifier_kernel<<<(prm.G + 255) / 256, 256, 0, stream>>>(
        prm.pooled, cntG, prm.Wc1, prm.bc1, prm.Wc2, prm.bc2, prm.outp, prm.G);
  }
}